// Round 7
// baseline (1342.066 us; speedup 1.0000x reference)
//
#include <hip/hip_runtime.h>
#include <stdint.h>

#define N 2048
#define BATCH 8
#define NROWS (BATCH * N)   // 16384
#define CAPN 256            // shortlist capacity per row

typedef unsigned long long u64;
typedef unsigned u32;

#define DEADK 0xFFFFFFFFFFFFFFFFull

// ---------------- DPP wave64 reductions -----------------------------------
__device__ __forceinline__ unsigned wave_umin_bcast(unsigned x) {
#define DPP_MIN(ctrl)                                                          \
  {                                                                            \
    unsigned t = (unsigned)__builtin_amdgcn_update_dpp((int)x, (int)x, ctrl,   \
                                                       0xf, 0xf, false);       \
    x = t < x ? t : x;                                                         \
  }
  DPP_MIN(0x111) DPP_MIN(0x112) DPP_MIN(0x114) DPP_MIN(0x118)
  DPP_MIN(0x142) DPP_MIN(0x143)
#undef DPP_MIN
  return (unsigned)__builtin_amdgcn_readlane((int)x, 63);
}

__device__ __forceinline__ unsigned wave_umax_bcast(unsigned x) {
#define DPP_MAX(ctrl)                                                          \
  {                                                                            \
    unsigned t = (unsigned)__builtin_amdgcn_update_dpp((int)x, (int)x, ctrl,   \
                                                       0xf, 0xf, false);       \
    x = t > x ? t : x;                                                         \
  }
  DPP_MAX(0x111) DPP_MAX(0x112) DPP_MAX(0x114) DPP_MAX(0x118)
  DPP_MAX(0x142) DPP_MAX(0x143)
#undef DPP_MAX
  return (unsigned)__builtin_amdgcn_readlane((int)x, 63);
}

#define DPP64_MIN(x, ctrl)                                                     \
  {                                                                            \
    u32 lo_ = (u32)(x), hi_ = (u32)((x) >> 32);                                \
    u32 tlo_ = (u32)__builtin_amdgcn_update_dpp((int)lo_, (int)lo_, (ctrl),    \
                                                0xf, 0xf, false);              \
    u32 thi_ = (u32)__builtin_amdgcn_update_dpp((int)hi_, (int)hi_, (ctrl),    \
                                                0xf, 0xf, false);              \
    u64 t_ = ((u64)thi_ << 32) | tlo_;                                         \
    x = t_ < x ? t_ : x;                                                       \
  }

__device__ __forceinline__ u64 wave_min64_l63(u64 x) {
  DPP64_MIN(x, 0x111) DPP64_MIN(x, 0x112) DPP64_MIN(x, 0x114)
  DPP64_MIN(x, 0x118) DPP64_MIN(x, 0x142) DPP64_MIN(x, 0x143)
  return x;
}

// Exact-order distance: ((dx*dx + dy*dy) + dz*dz), no FMA contraction, sqrtf.
#define DIST(qx, qy, qz, TX, TY, TZ, j, dout)                                  \
  do {                                                                         \
    _Pragma("clang fp contract(off)")                                          \
    float dx_ = (qx) - (TX)[j];                                                \
    float dy_ = (qy) - (TY)[j];                                                \
    float dz_ = (qz) - (TZ)[j];                                                \
    float s_ = dx_ * dx_ + dy_ * dy_ + dz_ * dz_;                              \
    dout = sqrtf(s_);                                                          \
  } while (0)

// ---------------- Phase 1a: tau-shortlist (proven R2-R6) -------------------
__global__ __launch_bounds__(256, 1)
void emd_shortlist_kernel(const float* __restrict__ pred,
                          const float* __restrict__ target,
                          u64* __restrict__ keys,
                          u32* __restrict__ cnts) {
    __shared__ float tx[N], ty[N], tz[N];
    const int b  = blockIdx.x >> 9;
    const int r0 = (blockIdx.x & 511) << 2;
    const float* tb = target + (size_t)b * N * 3;

    for (int idx = threadIdx.x; idx < 3 * N; idx += 256) {
        float v = tb[idx];
        int n = idx / 3, c = idx - 3 * n;
        if (c == 0) tx[n] = v; else if (c == 1) ty[n] = v; else tz[n] = v;
    }
    __syncthreads();

    const int wid = threadIdx.x >> 6, lane = threadIdx.x & 63;
    const int i = r0 + wid;
    const size_t row = (size_t)b * N + i;
    const float* pb = pred + row * 3;
    const float qx = pb[0], qy = pb[1], qz = pb[2];

    float d[32];
    float m = 3.4e38f;
    #pragma unroll
    for (int c = 0; c < 32; ++c) {
        const int j = (c << 6) + lane;
        float dd;
        DIST(qx, qy, qz, tx, ty, tz, j, dd);
        d[c] = dd;
        m = fminf(m, dd);
    }

    unsigned mb = __float_as_uint(m);
    {   // pair-min (xor1 quad_perm): tau = max of 32 min-of-64 -> E[cnt]~130
        unsigned t = (unsigned)__builtin_amdgcn_update_dpp((int)mb, (int)mb,
                                                           0x0B1, 0xf, 0xf, false);
        mb = t < mb ? t : mb;
    }
    const unsigned tau = wave_umax_bcast(mb);
    const float tauf = __uint_as_float(tau);

    u64* krow = keys + row * (size_t)CAPN;
    unsigned base = 0;
    #pragma unroll
    for (int c = 0; c < 32; ++c) {
        const bool p = d[c] <= tauf;
        const u64 bm = __ballot(p);
        if (p) {
            unsigned off = base + (unsigned)__popcll(bm & ((1ull << lane) - 1ull));
            if (off < (unsigned)CAPN)
                krow[off] = ((u64)__float_as_uint(d[c]) << 32) |
                            (unsigned)((c << 6) + lane);
        }
        base += (unsigned)__popcll(bm);
    }
    if (lane == 0) cnts[row] = base;
}

// ---------------- Phase 1b: in-place sorted top-64 extraction --------------
#define CSWAP(a, b)                                                            \
  { u64 mn_ = (a) < (b) ? (a) : (b); u64 mx_ = (a) < (b) ? (b) : (a);          \
    (a) = mn_; (b) = mx_; }

__global__ __launch_bounds__(256, 1)
void emd_sort64_kernel(u64* __restrict__ keys, const u32* __restrict__ cnts) {
    const int wid = threadIdx.x >> 6, lane = threadIdx.x & 63;
    const size_t row = (size_t)blockIdx.x * 4 + wid;
    u64* krow = keys + row * (size_t)CAPN;

    const u32 cnt = cnts[row];
    const u32 lim = (cnt > (u32)CAPN) ? 0u : cnt;   // overflow -> no candidates

    u64 k0 = ((u32)lane       < lim) ? krow[lane      ] : DEADK;
    u64 k1 = ((u32)lane + 64  < lim) ? krow[lane + 64 ] : DEADK;
    u64 k2 = ((u32)lane + 128 < lim) ? krow[lane + 128] : DEADK;
    u64 k3 = ((u32)lane + 192 < lim) ? krow[lane + 192] : DEADK;

    CSWAP(k0, k1) CSWAP(k2, k3) CSWAP(k0, k2) CSWAP(k1, k3) CSWAP(k1, k2)

    u64 mykey = DEADK;
    for (int it = 0; it < 64; ++it) {
        u64 wm = wave_min64_l63(k0);
        u32 wlo = (u32)__builtin_amdgcn_readlane((int)(u32)wm, 63);
        u32 whi = (u32)__builtin_amdgcn_readlane((int)(u32)(wm >> 32), 63);
        if (whi == 0xFFFFFFFFu) break;            // all exhausted (cnt < 64)
        const u64 wkey = ((u64)whi << 32) | wlo;
        mykey = (lane == it) ? wkey : mykey;      // capture in lane `it`
        const bool eq = (k0 == wkey);             // unique (distinct j)
        k0 = eq ? k1 : k0; k1 = eq ? k2 : k1; k2 = eq ? k3 : k2;
        k3 = eq ? DEADK : k3;
    }
    krow[lane] = mykey;   // in-place: all reads consumed above
}

// ---------------- Phase 2: block-speculative all-register greedy -----------
// 64 rows/block; lane l owns row i0+l with its top-16 sorted candidates in
// 16 named u64 registers (queue; front = current pick jcur/dcur). Consumed
// bitmask is DISTRIBUTED: lane w owns word w in register mw -- commit is pure
// VALU; aliveness of a new queue-front is one __shfl (bpermute). The serial
// per-row chain has NO memory operations. Exact: sorted prefix of the
// prefix-closed tau-set, fronts tested against the live mask; tier-2 = stored
// top-64 (ballot+ffs); tier-3 = full distance scan vs mask (always exact).
__global__ __launch_bounds__(64, 1)
void emd_greedy_spec_kernel(const float* __restrict__ pred,
                            const float* __restrict__ target,
                            const u64* __restrict__ keys,
                            float* __restrict__ batch_emd) {
    __shared__ float tx[N], ty[N], tz[N];
    __shared__ float qxs[N], qys[N], qzs[N];

    const int lane = threadIdx.x;
    const int b = blockIdx.x;
    const float* pb = pred + (size_t)b * N * 3;
    const float* tb = target + (size_t)b * N * 3;

    for (int idx = lane; idx < 3 * N; idx += 64) {
        float vp = pb[idx], vt = tb[idx];
        int n = idx / 3, c = idx - 3 * n;
        if (c == 0)      { qxs[n] = vp; tx[n] = vt; }
        else if (c == 1) { qys[n] = vp; ty[n] = vt; }
        else             { qzs[n] = vp; tz[n] = vt; }
    }
    // single wave: LDS program-ordered; used only by rare tier-3

    const u64* kb = keys + (size_t)b * N * (size_t)CAPN;

    u32 mw = 0;                         // lane w owns consumed-mask word w
    u32 jcur = 0xFFFFFFFEu;             // current pick (RETIRED sentinel)
    u32 dcur = 0;
    u64 c0,c1,c2,c3,c4,c5,c6,c7,c8,c9,c10,c11,c12,c13,c14,c15;
    double sum0 = 0.0, sum1 = 0.0;

    // Advance-and-settle: for lanes with advv set, pop queue fronts until an
    // alive front (-> jcur/dcur) or DEADK (-> EXH sentinel). Wave-uniform
    // while; body only runs when someone advances.
#define SETTLE(advv)                                                           \
    while (__ballot(advv)) {                                                   \
        const u32 jf = (u32)c0;                                                \
        const u32 df = (u32)(c0 >> 32);                                        \
        const bool isdead = (df == 0xFFFFFFFFu);                               \
        c0  = advv ? c1  : c0;   c1  = advv ? c2    : c1;                      \
        c2  = advv ? c3  : c2;   c3  = advv ? c4    : c3;                      \
        c4  = advv ? c5  : c4;   c5  = advv ? c6    : c5;                      \
        c6  = advv ? c7  : c6;   c7  = advv ? c8    : c7;                      \
        c8  = advv ? c9  : c8;   c9  = advv ? c10   : c9;                      \
        c10 = advv ? c11 : c10;  c11 = advv ? c12   : c11;                     \
        c12 = advv ? c13 : c12;  c13 = advv ? c14   : c13;                     \
        c14 = advv ? c15 : c14;  c15 = advv ? DEADK : c15;                     \
        const u32 w_ = (u32)__shfl((int)mw, (int)((jf >> 5) & 63), 64);        \
        const bool cons = ((w_ >> (jf & 31)) & 1u) != 0u;                      \
        const bool sd = advv && isdead;                                        \
        const bool sa = advv && !isdead && !cons;                              \
        jcur = sd ? 0xFFFFFFFFu : (sa ? jf : jcur);                            \
        dcur = sd ? 0xFFFFFFFFu : (sa ? df : dcur);                            \
        advv = advv && !sd && !sa;                                             \
    }

    for (int blk = 0; blk < N / 64; ++blk) {
        const int i0 = blk << 6;
        // refill: lane l <- top-16 of row i0+l (8 x 16B loads, once per block)
        const u64* rp = kb + (size_t)(i0 + lane) * CAPN;
        ulonglong2 p0 = *(const ulonglong2*)(rp + 0);
        ulonglong2 p1 = *(const ulonglong2*)(rp + 2);
        ulonglong2 p2 = *(const ulonglong2*)(rp + 4);
        ulonglong2 p3 = *(const ulonglong2*)(rp + 6);
        ulonglong2 p4 = *(const ulonglong2*)(rp + 8);
        ulonglong2 p5 = *(const ulonglong2*)(rp + 10);
        ulonglong2 p6 = *(const ulonglong2*)(rp + 12);
        ulonglong2 p7 = *(const ulonglong2*)(rp + 14);
        c0 = p0.x;  c1 = p0.y;  c2 = p1.x;  c3 = p1.y;
        c4 = p2.x;  c5 = p2.y;  c6 = p3.x;  c7 = p3.y;
        c8 = p4.x;  c9 = p4.y;  c10 = p5.x; c11 = p5.y;
        c12 = p6.x; c13 = p6.y; c14 = p7.x; c15 = p7.y;

        bool adv0 = true;
        SETTLE(adv0);

        for (int l = 0; l < 64; ++l) {
            u32 dw = (u32)__builtin_amdgcn_readlane((int)dcur, l);
            u32 jw = (u32)__builtin_amdgcn_readlane((int)jcur, l);
            if (__builtin_expect(dw == 0xFFFFFFFFu, 0)) {
                const int row = i0 + l;
                // tier-2: row's stored sorted top-64, one key per lane
                const u64 k2 = kb[(size_t)row * CAPN + lane];
                const u32 j2 = (u32)k2, d2 = (u32)(k2 >> 32);
                const u32 w2 = (u32)__shfl((int)mw, (int)((j2 >> 5) & 63), 64);
                const bool alive2 = (d2 != 0xFFFFFFFFu) &&
                                    !((w2 >> (j2 & 31)) & 1u);
                const u64 bal = __ballot(alive2);
                if (bal != 0ull) {
                    const int L = __ffsll((long long)bal) - 1;
                    dw = (u32)__builtin_amdgcn_readlane((int)d2, L);
                    jw = (u32)__builtin_amdgcn_readlane((int)j2, L);
                } else {
                    // tier-3: exact full scan vs distributed mask
                    const float qx = qxs[row], qy = qys[row], qz = qzs[row];
                    u32 dl = 0xFFFFFFFFu, jl = 0;
                    #pragma unroll 4
                    for (int c = 0; c < 32; ++c) {
                        const int j = (c << 6) + lane;
                        const u32 w = (u32)__shfl((int)mw,
                                                  (c << 1) + (lane >> 5), 64);
                        float dd;
                        DIST(qx, qy, qz, tx, ty, tz, j, dd);
                        const u32 db = __float_as_uint(dd);
                        if (!((w >> (j & 31)) & 1u) && db < dl) {
                            dl = db; jl = (u32)j;
                        }
                    }
                    const u32 dmin = wave_umin_bcast(dl);
                    const u32 jc = (dl == dmin) ? jl : 0xFFFFFFFFu;
                    jw = wave_umin_bcast(jc);
                    dw = dmin;
                }
            }
            // ---- commit (pure VALU/SALU) ----
            const float dv = __uint_as_float(dw);
            if (l & 1) sum1 += (double)dv; else sum0 += (double)dv;
            mw = (lane == (int)(jw >> 5)) ? (mw | (1u << (jw & 31))) : mw;
            if (lane == l) jcur = 0xFFFFFFFEu;          // retire own row
            bool adv = (jcur == jw);                    // killed picks advance
            SETTLE(adv);
        }
    }

    if (lane == 0) batch_emd[b] = (float)((sum0 + sum1) / N);
#undef SETTLE
}

// ---------------- exact full-scan helper (tiny-ws fallback kernel) --------
__device__ __forceinline__ u64 full_scan_row(
    int lane, float qx, float qy, float qz,
    const float* tx, const float* ty, const float* tz,
    const unsigned char* used) {
  u32 dl = 0xFFFFFFFFu, jl = 0u;
  #pragma unroll 8
  for (int c = 0; c < 32; ++c) {
    const int j = (c << 6) + lane;
    if (!used[j]) {
      float dd;
      DIST(qx, qy, qz, tx, ty, tz, j, dd);
      const u32 db = __float_as_uint(dd);
      if (db < dl) { dl = db; jl = (u32)j; }
    }
  }
  const u32 dmin = wave_umin_bcast(dl);
  const u32 jc = (dl == dmin) ? jl : 0xFFFFFFFFu;
  const u32 jmin = wave_umin_bcast(jc);
  return ((u64)dmin << 32) | jmin;
}

__global__ __launch_bounds__(64, 1)
void emd_greedy_full_kernel(const float* __restrict__ pred,
                            const float* __restrict__ target,
                            float* __restrict__ batch_emd) {
    __shared__ float tx[N], ty[N], tz[N];
    __shared__ float qxs[N], qys[N], qzs[N];
    __shared__ unsigned char used[N];

    const int lane = threadIdx.x;
    const int b = blockIdx.x;
    const float* pb = pred + (size_t)b * N * 3;
    const float* tb = target + (size_t)b * N * 3;

    for (int idx = lane; idx < 3 * N; idx += 64) {
        float vp = pb[idx], vt = tb[idx];
        int n = idx / 3, c = idx - 3 * n;
        if (c == 0)      { qxs[n] = vp; tx[n] = vt; }
        else if (c == 1) { qys[n] = vp; ty[n] = vt; }
        else             { qzs[n] = vp; tz[n] = vt; }
    }
    for (int j = lane; j < N; j += 64) used[j] = 0;

    double sum = 0.0;
    for (int i = 0; i < N; ++i) {
        u64 fs = full_scan_row(lane, qxs[i], qys[i], qzs[i], tx, ty, tz, used);
        sum += (double)__uint_as_float((u32)(fs >> 32));
        if (lane == 0) used[(u32)fs] = 1;
    }
    if (lane == 0) batch_emd[b] = (float)(sum / N);
}

__global__ void emd_mean_kernel(const float* __restrict__ batch_emd,
                                float* __restrict__ out) {
    double s = 0.0;
    for (int b = 0; b < BATCH; ++b) s += (double)batch_emd[b];
    out[0] = (float)(s / BATCH);
}

extern "C" void kernel_launch(void* const* d_in, const int* in_sizes, int n_in,
                              void* d_out, int out_size, void* d_ws, size_t ws_size,
                              hipStream_t stream) {
    const float* pred   = (const float*)d_in[0];
    const float* target = (const float*)d_in[1];
    float* out = (float*)d_out;
    char* wsb = (char*)d_ws;

    const size_t keysz = (size_t)NROWS * CAPN * 8;   // 33.6 MB
    const size_t cntsz = (size_t)NROWS * 4;

    if (ws_size >= keysz + cntsz + 32) {
        u64* keys = (u64*)wsb;
        u32* cnts = (u32*)(wsb + keysz);
        float* emd = (float*)(wsb + keysz + cntsz);
        emd_shortlist_kernel<<<NROWS / 4, 256, 0, stream>>>(pred, target, keys, cnts);
        emd_sort64_kernel<<<NROWS / 4, 256, 0, stream>>>(keys, cnts);
        emd_greedy_spec_kernel<<<BATCH, 64, 0, stream>>>(pred, target, keys, emd);
        emd_mean_kernel<<<1, 1, 0, stream>>>(emd, out);
    } else {
        float* emd = (float*)wsb;
        emd_greedy_full_kernel<<<BATCH, 64, 0, stream>>>(pred, target, emd);
        emd_mean_kernel<<<1, 1, 0, stream>>>(emd, out);
    }
}

// Round 8
// 1066.558 us; speedup vs baseline: 1.2583x; 1.2583x over previous
//
#include <hip/hip_runtime.h>
#include <stdint.h>

#define N 2048
#define BATCH 8
#define NROWS (BATCH * N)   // 16384
#define CAPN 256            // shortlist capacity per row

typedef unsigned long long u64;
typedef unsigned u32;

#define DEADK 0xFFFFFFFFFFFFFFFFull

// ---------------- DPP wave64 reductions -----------------------------------
__device__ __forceinline__ unsigned wave_umin_bcast(unsigned x) {
#define DPP_MIN(ctrl)                                                          \
  {                                                                            \
    unsigned t = (unsigned)__builtin_amdgcn_update_dpp((int)x, (int)x, ctrl,   \
                                                       0xf, 0xf, false);       \
    x = t < x ? t : x;                                                         \
  }
  DPP_MIN(0x111) DPP_MIN(0x112) DPP_MIN(0x114) DPP_MIN(0x118)
  DPP_MIN(0x142) DPP_MIN(0x143)
#undef DPP_MIN
  return (unsigned)__builtin_amdgcn_readlane((int)x, 63);
}

__device__ __forceinline__ unsigned wave_umax_bcast(unsigned x) {
#define DPP_MAX(ctrl)                                                          \
  {                                                                            \
    unsigned t = (unsigned)__builtin_amdgcn_update_dpp((int)x, (int)x, ctrl,   \
                                                       0xf, 0xf, false);       \
    x = t > x ? t : x;                                                         \
  }
  DPP_MAX(0x111) DPP_MAX(0x112) DPP_MAX(0x114) DPP_MAX(0x118)
  DPP_MAX(0x142) DPP_MAX(0x143)
#undef DPP_MAX
  return (unsigned)__builtin_amdgcn_readlane((int)x, 63);
}

#define DPP64_MIN(x, ctrl)                                                     \
  {                                                                            \
    u32 lo_ = (u32)(x), hi_ = (u32)((x) >> 32);                                \
    u32 tlo_ = (u32)__builtin_amdgcn_update_dpp((int)lo_, (int)lo_, (ctrl),    \
                                                0xf, 0xf, false);              \
    u32 thi_ = (u32)__builtin_amdgcn_update_dpp((int)hi_, (int)hi_, (ctrl),    \
                                                0xf, 0xf, false);              \
    u64 t_ = ((u64)thi_ << 32) | tlo_;                                         \
    x = t_ < x ? t_ : x;                                                       \
  }

__device__ __forceinline__ u64 wave_min64_l63(u64 x) {
  DPP64_MIN(x, 0x111) DPP64_MIN(x, 0x112) DPP64_MIN(x, 0x114)
  DPP64_MIN(x, 0x118) DPP64_MIN(x, 0x142) DPP64_MIN(x, 0x143)
  return x;
}

// Exact-order distance: ((dx*dx + dy*dy) + dz*dz), no FMA contraction, sqrtf.
#define DIST(qx, qy, qz, TX, TY, TZ, j, dout)                                  \
  do {                                                                         \
    _Pragma("clang fp contract(off)")                                          \
    float dx_ = (qx) - (TX)[j];                                                \
    float dy_ = (qy) - (TY)[j];                                                \
    float dz_ = (qz) - (TZ)[j];                                                \
    float s_ = dx_ * dx_ + dy_ * dy_ + dz_ * dz_;                              \
    dout = sqrtf(s_);                                                          \
  } while (0)

// ---------------- Phase 1a: tau-shortlist (proven R2-R7) -------------------
__global__ __launch_bounds__(256, 1)
void emd_shortlist_kernel(const float* __restrict__ pred,
                          const float* __restrict__ target,
                          u64* __restrict__ keys,
                          u32* __restrict__ cnts) {
    __shared__ float tx[N], ty[N], tz[N];
    const int b  = blockIdx.x >> 9;
    const int r0 = (blockIdx.x & 511) << 2;
    const float* tb = target + (size_t)b * N * 3;

    for (int idx = threadIdx.x; idx < 3 * N; idx += 256) {
        float v = tb[idx];
        int n = idx / 3, c = idx - 3 * n;
        if (c == 0) tx[n] = v; else if (c == 1) ty[n] = v; else tz[n] = v;
    }
    __syncthreads();

    const int wid = threadIdx.x >> 6, lane = threadIdx.x & 63;
    const int i = r0 + wid;
    const size_t row = (size_t)b * N + i;
    const float* pb = pred + row * 3;
    const float qx = pb[0], qy = pb[1], qz = pb[2];

    float d[32];
    float m = 3.4e38f;
    #pragma unroll
    for (int c = 0; c < 32; ++c) {
        const int j = (c << 6) + lane;
        float dd;
        DIST(qx, qy, qz, tx, ty, tz, j, dd);
        d[c] = dd;
        m = fminf(m, dd);
    }

    unsigned mb = __float_as_uint(m);
    {   // pair-min (xor1 quad_perm): tau = max of 32 min-of-64 -> E[cnt]~130
        unsigned t = (unsigned)__builtin_amdgcn_update_dpp((int)mb, (int)mb,
                                                           0x0B1, 0xf, 0xf, false);
        mb = t < mb ? t : mb;
    }
    const unsigned tau = wave_umax_bcast(mb);
    const float tauf = __uint_as_float(tau);

    u64* krow = keys + row * (size_t)CAPN;
    unsigned base = 0;
    #pragma unroll
    for (int c = 0; c < 32; ++c) {
        const bool p = d[c] <= tauf;
        const u64 bm = __ballot(p);
        if (p) {
            unsigned off = base + (unsigned)__popcll(bm & ((1ull << lane) - 1ull));
            if (off < (unsigned)CAPN)
                krow[off] = ((u64)__float_as_uint(d[c]) << 32) |
                            (unsigned)((c << 6) + lane);
        }
        base += (unsigned)__popcll(bm);
    }
    if (lane == 0) cnts[row] = base;
}

// ---------------- Phase 1b: in-place sorted top-64 extraction --------------
#define CSWAP(a, b)                                                            \
  { u64 mn_ = (a) < (b) ? (a) : (b); u64 mx_ = (a) < (b) ? (b) : (a);          \
    (a) = mn_; (b) = mx_; }

__global__ __launch_bounds__(256, 1)
void emd_sort64_kernel(u64* __restrict__ keys, const u32* __restrict__ cnts) {
    const int wid = threadIdx.x >> 6, lane = threadIdx.x & 63;
    const size_t row = (size_t)blockIdx.x * 4 + wid;
    u64* krow = keys + row * (size_t)CAPN;

    const u32 cnt = cnts[row];
    const u32 lim = (cnt > (u32)CAPN) ? 0u : cnt;   // overflow -> no candidates

    u64 k0 = ((u32)lane       < lim) ? krow[lane      ] : DEADK;
    u64 k1 = ((u32)lane + 64  < lim) ? krow[lane + 64 ] : DEADK;
    u64 k2 = ((u32)lane + 128 < lim) ? krow[lane + 128] : DEADK;
    u64 k3 = ((u32)lane + 192 < lim) ? krow[lane + 192] : DEADK;

    CSWAP(k0, k1) CSWAP(k2, k3) CSWAP(k0, k2) CSWAP(k1, k3) CSWAP(k1, k2)

    u64 mykey = DEADK;
    for (int it = 0; it < 64; ++it) {
        u64 wm = wave_min64_l63(k0);
        u32 wlo = (u32)__builtin_amdgcn_readlane((int)(u32)wm, 63);
        u32 whi = (u32)__builtin_amdgcn_readlane((int)(u32)(wm >> 32), 63);
        if (whi == 0xFFFFFFFFu) break;            // all exhausted (cnt < 64)
        const u64 wkey = ((u64)whi << 32) | wlo;
        mykey = (lane == it) ? wkey : mykey;      // capture in lane `it`
        const bool eq = (k0 == wkey);             // unique (distinct j)
        k0 = eq ? k1 : k0; k1 = eq ? k2 : k1; k2 = eq ? k3 : k2;
        k3 = eq ? DEADK : k3;
    }
    krow[lane] = mykey;   // in-place: all reads consumed above
}

// ---------------- Phase 2: prefix-parallel committing greedy ---------------
// Lane l owns row i0+l; sorted top-16 candidates in named registers. Per STEP
// (amortized over ~many rows): settle consumed fronts vs LDS bitmask, claim
// fronts via LDS atomicMin (min lane = min row wins), c = first failing lane
// (lost claim or exhausted); lanes < c all commit simultaneously -- EXACT:
// committed fronts are distinct; each is its row's true argmin (sorted prefix
// of the prefix-closed tau-set, consumed entries popped); consuming other
// targets cannot create a smaller candidate; first conflict cuts the prefix.
// Exhausted row at the cut resolved via tier-2 (stored top-64) / tier-3
// (full scan) -- both exact. No exec-mask games in the hot path (dummy-slot
// predication for claim and mask-OR).
#define POPQ(advv)                                                             \
    c0 = advv ? c1 : c0;   c1 = advv ? c2  : c1;   c2 = advv ? c3  : c2;       \
    c3 = advv ? c4 : c3;   c4 = advv ? c5  : c4;   c5 = advv ? c6  : c5;       \
    c6 = advv ? c7 : c6;   c7 = advv ? c8  : c7;   c8 = advv ? c9  : c8;       \
    c9 = advv ? c10 : c9;  c10 = advv ? c11 : c10; c11 = advv ? c12 : c11;     \
    c12 = advv ? c13 : c12; c13 = advv ? c14 : c13; c14 = advv ? c15 : c14;    \
    c15 = advv ? DEADK : c15;

__global__ __launch_bounds__(64, 1)
void emd_greedy_step_kernel(const float* __restrict__ pred,
                            const float* __restrict__ target,
                            const u64* __restrict__ keys,
                            float* __restrict__ batch_emd) {
    __shared__ float tx[N], ty[N], tz[N];
    __shared__ float qxs[N], qys[N], qzs[N];
    __shared__ u32 maskLDS[128];        // words 0..63 = consumed bits; 64..127 scribble
    __shared__ u32 claim[N + 64];       // claim slots + 64 dummy slots
    __shared__ double dsum[64];

    const int lane = threadIdx.x;
    const int b = blockIdx.x;
    const float* pb = pred + (size_t)b * N * 3;
    const float* tb = target + (size_t)b * N * 3;

    for (int idx = lane; idx < 3 * N; idx += 64) {
        float vp = pb[idx], vt = tb[idx];
        int n = idx / 3, c = idx - 3 * n;
        if (c == 0)      { qxs[n] = vp; tx[n] = vt; }
        else if (c == 1) { qys[n] = vp; ty[n] = vt; }
        else             { qzs[n] = vp; tz[n] = vt; }
    }
    for (int w = lane; w < 128; w += 64) maskLDS[w] = 0;
    for (int w = lane; w < N + 64; w += 64) claim[w] = 0xFFFFFFFFu;
    // single wave: LDS program-ordered; no barriers needed

    const u64* kb = keys + (size_t)b * N * (size_t)CAPN;
    double sum_lane = 0.0;

    for (int blk = 0; blk < N / 64; ++blk) {
        const int i0 = blk << 6;
        const u64* rp = kb + (size_t)(i0 + lane) * CAPN;
        ulonglong2 p0 = *(const ulonglong2*)(rp + 0);
        ulonglong2 p1 = *(const ulonglong2*)(rp + 2);
        ulonglong2 p2 = *(const ulonglong2*)(rp + 4);
        ulonglong2 p3 = *(const ulonglong2*)(rp + 6);
        ulonglong2 p4 = *(const ulonglong2*)(rp + 8);
        ulonglong2 p5 = *(const ulonglong2*)(rp + 10);
        ulonglong2 p6 = *(const ulonglong2*)(rp + 12);
        ulonglong2 p7 = *(const ulonglong2*)(rp + 14);
        u64 c0 = p0.x,  c1 = p0.y,  c2 = p1.x,  c3 = p1.y;
        u64 c4 = p2.x,  c5 = p2.y,  c6 = p3.x,  c7 = p3.y;
        u64 c8 = p4.x,  c9 = p4.y,  c10 = p5.x, c11 = p5.y;
        u64 c12 = p6.x, c13 = p6.y, c14 = p7.x, c15 = p7.y;

        bool active = true;

        while (__ballot(active)) {
            // ---- settle: pop consumed fronts (lazy) ----
            bool chk = active;
            while (__ballot(chk)) {
                const u32 f = (u32)c0;
                const u32 dhi = (u32)(c0 >> 32);
                const u32 w = maskLDS[(f >> 5) & 63];
                const bool isdead = (dhi == 0xFFFFFFFFu);
                const bool cons = (!isdead) && (((w >> (f & 31)) & 1u) != 0u);
                const bool adv = chk && cons;
                POPQ(adv)
                chk = adv;
            }
            // ---- claim fronts (min lane = min row wins) ----
            const u32 f = (u32)c0;
            const u32 dhi = (u32)(c0 >> 32);
            const bool exh = active && (dhi == 0xFFFFFFFFu);
            const bool prop = active && !exh;
            const u32 feff = prop ? f : (u32)(N + lane);   // dummy slot
            atomicMin(&claim[feff], (u32)lane);
            const u32 win = claim[feff];
            claim[feff] = 0xFFFFFFFFu;                     // reset for next step
            const bool fail = active && (exh || (win != (u32)lane));
            const u64 fm = __ballot(fail);
            const u32 c = fm ? (u32)(__ffsll((long long)fm) - 1) : 64u;
            // ---- prefix commit: all active lanes < c ----
            const bool committed = active && ((u32)lane < c);
            const u32 oaddr = committed ? ((f >> 5) & 63u) : (64u + (u32)lane);
            atomicOr(&maskLDS[oaddr], committed ? (1u << (f & 31)) : 0u);
            sum_lane += committed ? (double)__uint_as_float(dhi) : 0.0;
            active = active && !committed;
            // ---- resolve an exhausted row blocking the prefix ----
            if (c < 64u) {
                const u64 em = __ballot(exh);
                if ((em >> c) & 1ull) {
                    const int row = i0 + (int)c;
                    // tier-2: stored sorted top-64, one key per lane
                    const u64 k2 = kb[(size_t)row * CAPN + lane];
                    const u32 j2 = (u32)k2, d2 = (u32)(k2 >> 32);
                    const u32 w2 = maskLDS[(j2 >> 5) & 63];
                    const bool alive2 = (d2 != 0xFFFFFFFFu) &&
                                        !((w2 >> (j2 & 31)) & 1u);
                    const u64 bal = __ballot(alive2);
                    u32 dw, jw;
                    if (bal != 0ull) {
                        const int L = __ffsll((long long)bal) - 1;
                        dw = (u32)__builtin_amdgcn_readlane((int)d2, L);
                        jw = (u32)__builtin_amdgcn_readlane((int)j2, L);
                    } else {
                        // tier-3: exact full scan vs bitmask
                        const float qx = qxs[row], qy = qys[row], qz = qzs[row];
                        u32 dl = 0xFFFFFFFFu, jl = 0;
                        #pragma unroll 4
                        for (int cc = 0; cc < 32; ++cc) {
                            const int j = (cc << 6) + lane;
                            const u32 w = maskLDS[j >> 5];
                            float dd;
                            DIST(qx, qy, qz, tx, ty, tz, j, dd);
                            const u32 db = __float_as_uint(dd);
                            if (!((w >> (j & 31)) & 1u) && db < dl) {
                                dl = db; jl = (u32)j;
                            }
                        }
                        const u32 dmin = wave_umin_bcast(dl);
                        const u32 jc = (dl == dmin) ? jl : 0xFFFFFFFFu;
                        jw = wave_umin_bcast(jc);
                        dw = dmin;
                    }
                    sum_lane += (lane == 0) ? (double)__uint_as_float(dw) : 0.0;
                    if (lane == 0)
                        atomicOr(&maskLDS[(jw >> 5) & 63], 1u << (jw & 31));
                    active = active && (lane != (int)c);
                }
            }
        }
    }

    dsum[lane] = sum_lane;
    if (lane == 0) {
        double s = 0.0;
        for (int t = 0; t < 64; ++t) s += dsum[t];
        batch_emd[b] = (float)(s / N);
    }
}

// ---------------- exact full-scan helper (tiny-ws fallback kernel) --------
__device__ __forceinline__ u64 full_scan_row(
    int lane, float qx, float qy, float qz,
    const float* tx, const float* ty, const float* tz,
    const unsigned char* used) {
  u32 dl = 0xFFFFFFFFu, jl = 0u;
  #pragma unroll 8
  for (int c = 0; c < 32; ++c) {
    const int j = (c << 6) + lane;
    if (!used[j]) {
      float dd;
      DIST(qx, qy, qz, tx, ty, tz, j, dd);
      const u32 db = __float_as_uint(dd);
      if (db < dl) { dl = db; jl = (u32)j; }
    }
  }
  const u32 dmin = wave_umin_bcast(dl);
  const u32 jc = (dl == dmin) ? jl : 0xFFFFFFFFu;
  const u32 jmin = wave_umin_bcast(jc);
  return ((u64)dmin << 32) | jmin;
}

__global__ __launch_bounds__(64, 1)
void emd_greedy_full_kernel(const float* __restrict__ pred,
                            const float* __restrict__ target,
                            float* __restrict__ batch_emd) {
    __shared__ float tx[N], ty[N], tz[N];
    __shared__ float qxs[N], qys[N], qzs[N];
    __shared__ unsigned char used[N];

    const int lane = threadIdx.x;
    const int b = blockIdx.x;
    const float* pb = pred + (size_t)b * N * 3;
    const float* tb = target + (size_t)b * N * 3;

    for (int idx = lane; idx < 3 * N; idx += 64) {
        float vp = pb[idx], vt = tb[idx];
        int n = idx / 3, c = idx - 3 * n;
        if (c == 0)      { qxs[n] = vp; tx[n] = vt; }
        else if (c == 1) { qys[n] = vp; ty[n] = vt; }
        else             { qzs[n] = vp; tz[n] = vt; }
    }
    for (int j = lane; j < N; j += 64) used[j] = 0;

    double sum = 0.0;
    for (int i = 0; i < N; ++i) {
        u64 fs = full_scan_row(lane, qxs[i], qys[i], qzs[i], tx, ty, tz, used);
        sum += (double)__uint_as_float((u32)(fs >> 32));
        if (lane == 0) used[(u32)fs] = 1;
    }
    if (lane == 0) batch_emd[b] = (float)(sum / N);
}

__global__ void emd_mean_kernel(const float* __restrict__ batch_emd,
                                float* __restrict__ out) {
    double s = 0.0;
    for (int b = 0; b < BATCH; ++b) s += (double)batch_emd[b];
    out[0] = (float)(s / BATCH);
}

extern "C" void kernel_launch(void* const* d_in, const int* in_sizes, int n_in,
                              void* d_out, int out_size, void* d_ws, size_t ws_size,
                              hipStream_t stream) {
    const float* pred   = (const float*)d_in[0];
    const float* target = (const float*)d_in[1];
    float* out = (float*)d_out;
    char* wsb = (char*)d_ws;

    const size_t keysz = (size_t)NROWS * CAPN * 8;   // 33.6 MB
    const size_t cntsz = (size_t)NROWS * 4;

    if (ws_size >= keysz + cntsz + 32) {
        u64* keys = (u64*)wsb;
        u32* cnts = (u32*)(wsb + keysz);
        float* emd = (float*)(wsb + keysz + cntsz);
        emd_shortlist_kernel<<<NROWS / 4, 256, 0, stream>>>(pred, target, keys, cnts);
        emd_sort64_kernel<<<NROWS / 4, 256, 0, stream>>>(keys, cnts);
        emd_greedy_step_kernel<<<BATCH, 64, 0, stream>>>(pred, target, keys, emd);
        emd_mean_kernel<<<1, 1, 0, stream>>>(emd, out);
    } else {
        float* emd = (float*)wsb;
        emd_greedy_full_kernel<<<BATCH, 64, 0, stream>>>(pred, target, emd);
        emd_mean_kernel<<<1, 1, 0, stream>>>(emd, out);
    }
}